// Round 1
// baseline (586.034 us; speedup 1.0000x reference)
//
#include <hip/hip_runtime.h>

// out[b, f, s] = x[b, 0, s] * w[f, s] + bias[f, s]
// B=128, F=256, S=4096  -> out: 134,217,728 fp32 (536.9 MB)
// Write-BW bound: one thread per float4 of output, pure shift/mask indexing.

#define BATCH 128
#define NFILT 256
#define SEQ   4096
#define SEQ4  (SEQ / 4)          // 1024 float4 per row
#define TOTAL4 ((size_t)BATCH * NFILT * SEQ4)  // 33,554,432 float4

__global__ __launch_bounds__(256) void dfe_kernel(
    const float* __restrict__ x,      // [BATCH, SEQ]
    const float* __restrict__ w,      // [NFILT, SEQ]
    const float* __restrict__ bias,   // [NFILT, SEQ]
    float* __restrict__ out)          // [BATCH, NFILT, SEQ]
{
    size_t tid = (size_t)blockIdx.x * blockDim.x + threadIdx.x;
    if (tid >= TOTAL4) return;

    size_t s4 = tid & (SEQ4 - 1);     // position within row (float4 units)
    size_t bf = tid >> 10;            // b * NFILT + f
    size_t f  = bf & (NFILT - 1);
    size_t b  = bf >> 8;

    const float4 x4 = ((const float4*)x)[b * SEQ4 + s4];
    const float4 w4 = ((const float4*)w)[f * SEQ4 + s4];
    const float4 b4 = ((const float4*)bias)[f * SEQ4 + s4];

    float4 o;
    o.x = fmaf(x4.x, w4.x, b4.x);
    o.y = fmaf(x4.y, w4.y, b4.y);
    o.z = fmaf(x4.z, w4.z, b4.z);
    o.w = fmaf(x4.w, w4.w, b4.w);

    ((float4*)out)[tid] = o;
}

extern "C" void kernel_launch(void* const* d_in, const int* in_sizes, int n_in,
                              void* d_out, int out_size, void* d_ws, size_t ws_size,
                              hipStream_t stream) {
    const float* x    = (const float*)d_in[0];   // (128, 1, 4096) fp32
    const float* w    = (const float*)d_in[1];   // (256, 4096)    fp32
    const float* bias = (const float*)d_in[2];   // (256, 4096)    fp32
    float* out = (float*)d_out;                  // (128, 256, 4096) fp32

    const int block = 256;
    const size_t grid = (TOTAL4 + block - 1) / block;  // 131072 blocks
    dfe_kernel<<<dim3((unsigned)grid), dim3(block), 0, stream>>>(x, w, bias, out);
}